// Round 6
// baseline (397.225 us; speedup 1.0000x reference)
//
#include <hip/hip_runtime.h>
#include <math.h>

// Capsule routing without materializing u_hat.
//   o[b,n,:] = W_n * (sum_i c[b,n,i] u[b,i,:])
//   logits[b,i,n] = u[b,i,:] . t[b,n,:],  t = W_n^T o_norm
// R6: - k_route retiled to 256i x 32n per block (4i x 8n per thread): 3
//       ds_read_b128 per 32 FMA (was 4 per 32) -> less LDS-pipe-bound.
//     - k_ot v5: block per (n, 16 b): W_n L2 traffic 256MB -> 16MB/launch
//       (R5's v4 was ~40us, W-bound); s fragments hoisted in registers.
//     - R5's global-gather GEMM reverted (97us: address-divergent loads).

#define B   64
#define IN  1024
#define ID  256
#define NC  32
#define DC  64
#define CH  4
#define RIT (IN / CH)   // 256 i per chunk

// ---------------------------------------------------------------------------
// sp0[c][b][d] = sum over i-chunk c of u[b][i][d]
__global__ __launch_bounds__(256) void k_sumu(const float* __restrict__ u,
                                              float* __restrict__ sp0) {
    const int c = blockIdx.x, b = blockIdx.y;
    const int d = threadIdx.x;
    const float* up = u + ((size_t)b * IN + (size_t)c * RIT) * ID + d;
    float acc = 0.f;
#pragma unroll 8
    for (int i = 0; i < RIT; ++i) acc += up[(size_t)i * ID];
    sp0[(c * B + b) * ID + d] = acc;
}

// ---------------------------------------------------------------------------
// Block = (n, group of 16 b). 256 threads = 4 waves.
//   A: S[16][256] in LDS from partials (coalesced).
//   B: o[b][d] = S[b][:] . W[d][:]  — wave w does rows d=w*16+rr; W row read
//      coalesced once, dot vs 16 register-held s-fragments, butterfly per b.
//   C: normalize (mode 0/1) or squash->out (mode 2), wave per 4 b.
//   D: t[b][k] = sum_d on[b][d] W[d][k] — thread per k-quad, 4 b each;
//      W rows coalesced, on via LDS broadcast.
__global__ __launch_bounds__(256) void k_ot(const float* __restrict__ W,
                                            const float* __restrict__ src,
                                            float* __restrict__ tout,
                                            const int mode) {
    const int n = blockIdx.x, b0 = blockIdx.y * 16;
    __shared__ float S[16][ID];
    __shared__ float o_lds[16][DC];
    __shared__ float on_lds[16][DC];
    const int tid = threadIdx.x;
    const int wave = tid >> 6, lane = tid & 63;
    const float* Wn = W + (size_t)n * DC * ID;

    // phase A: S[bb][k] = reduced partials (4 chunks), float4-vectorized.
    {
        const float4* s4 = (const float4*)src;
#pragma unroll
        for (int a = 0; a < 4; ++a) {
            const int idx = a * 256 + tid;          // 1024 = 16 bb x 64 kq
            const int bb = idx >> 6, kq = idx & 63;
            float4 acc = make_float4(0.f, 0.f, 0.f, 0.f);
            if (mode == 0) {
#pragma unroll
                for (int c = 0; c < CH; ++c) {
                    const float4 v = s4[(size_t)(c * B + b0 + bb) * (ID / 4) + kq];
                    acc.x += v.x; acc.y += v.y; acc.z += v.z; acc.w += v.w;
                }
                acc.x *= (1.0f / NC); acc.y *= (1.0f / NC);
                acc.z *= (1.0f / NC); acc.w *= (1.0f / NC);
            } else {
#pragma unroll
                for (int c = 0; c < CH; ++c) {
                    const float4 v =
                        s4[((size_t)(c * B + b0 + bb) * NC + n) * (ID / 4) + kq];
                    acc.x += v.x; acc.y += v.y; acc.z += v.z; acc.w += v.w;
                }
            }
            *(float4*)&S[bb][kq * 4] = acc;
        }
    }
    __syncthreads();

    // phase B: wave w computes rows d = w*16..w*16+15 for all 16 b.
    // Two halves of 8 b: 8 s-fragments hoisted in registers per half.
#pragma unroll
    for (int h = 0; h < 2; ++h) {
        float4 sb[8];
#pragma unroll
        for (int j = 0; j < 8; ++j) sb[j] = *(const float4*)&S[h * 8 + j][lane * 4];
#pragma unroll 4
        for (int rr = 0; rr < 16; ++rr) {
            const int d = wave * 16 + rr;
            const float4 w4 = *(const float4*)(Wn + (size_t)d * ID + lane * 4);
#pragma unroll
            for (int j = 0; j < 8; ++j) {
                float p = w4.x * sb[j].x + w4.y * sb[j].y
                        + w4.z * sb[j].z + w4.w * sb[j].w;
#pragma unroll
                for (int off = 32; off > 0; off >>= 1) p += __shfl_xor(p, off);
                if (lane == 0) o_lds[h * 8 + j][d] = p;
            }
        }
    }
    __syncthreads();

    // phase C: wave handles 4 b; lane = d. norm (0/1) or squash->out (2).
    {
#pragma unroll
        for (int j = 0; j < 4; ++j) {
            const int bb = wave * 4 + j;
            const float v = o_lds[bb][lane];
            float sq = v * v;
#pragma unroll
            for (int off = 32; off > 0; off >>= 1) sq += __shfl_xor(sq, off);
            if (mode == 2) {
                const float s2 = sq + 1e-7f;
                tout[(size_t)((b0 + bb) * NC + n) * DC + lane] =
                    v * (sqrtf(s2) / (0.5f + s2));
            } else {
                on_lds[bb][lane] = v / fmaxf(sqrtf(sq), 1e-12f);
            }
        }
    }
    if (mode == 2) return;
    __syncthreads();

    // phase D: thread = (bg, kq); 4 b per thread. W rows coalesced; on bcast.
    {
        const int kq = tid & 63, bg = tid >> 6;
        float4 acc[4];
#pragma unroll
        for (int j = 0; j < 4; ++j) acc[j] = make_float4(0.f, 0.f, 0.f, 0.f);
#pragma unroll 8
        for (int d = 0; d < DC; ++d) {
            const float4 w4 = *(const float4*)(Wn + (size_t)d * ID + kq * 4);
#pragma unroll
            for (int j = 0; j < 4; ++j) {
                const float od = on_lds[bg * 4 + j][d];
                acc[j].x += w4.x * od; acc[j].y += w4.y * od;
                acc[j].z += w4.z * od; acc[j].w += w4.w * od;
            }
        }
#pragma unroll
        for (int j = 0; j < 4; ++j) {
            const int b = b0 + bg * 4 + j;
            *(float4*)(tout + ((size_t)b * NC + n) * ID + kq * 4) = acc[j];
        }
    }
}

// ---------------------------------------------------------------------------
// Fused logits (256i x 32n, K=256) -> softmax over n -> aggregate partials.
// Per thread: 4 i x 8 n. LDS-staged A (double-buffered) + full B tile.
__global__ __launch_bounds__(256) void k_route(const float* __restrict__ u,
                                               const float* __restrict__ t,
                                               float* __restrict__ sp) {
    const int c = blockIdx.x, b = blockIdx.y;
    const int iBase = c * RIT;
    __shared__ float Ts[ID][36];        // t[b] transposed: Ts[k][n]
    __shared__ float cl[RIT][36];       // logits -> coefficients (36.9 KB)
    __shared__ float Us[2][16][260];    // dbuf u chunk transposed: Us[k][i]
    const int tid = threadIdx.x;

    // Ts[k][n] = t[b][n][k]
    {
        const float* tb = t + (size_t)b * NC * ID;
#pragma unroll
        for (int n = 0; n < NC; ++n) Ts[tid][n] = tb[(size_t)n * ID + tid];
    }

    const int q = tid >> 2, r = tid & 3;          // 4 i (q) x 8 n (r)
    const float* ub = u + ((size_t)b * IN + iBase) * ID;

    // staging role: 4 reps of (i, k-quad)
    // prologue: chunk 0 -> buffer 0
    {
#pragma unroll
        for (int rep = 0; rep < 4; ++rep) {
            const int f = tid + rep * 256;
            const int i = f >> 2, c4 = f & 3;
            const float4 v = *(const float4*)(ub + (size_t)i * ID + c4 * 4);
            Us[0][c4 * 4 + 0][i] = v.x;  Us[0][c4 * 4 + 1][i] = v.y;
            Us[0][c4 * 4 + 2][i] = v.z;  Us[0][c4 * 4 + 3][i] = v.w;
        }
    }

    float acc4[4][8];
#pragma unroll
    for (int ii = 0; ii < 4; ++ii)
#pragma unroll
        for (int jj = 0; jj < 8; ++jj) acc4[ii][jj] = 0.f;

    for (int kc = 0; kc < ID / 16; ++kc) {
        __syncthreads();
        const int cb = kc & 1, nb = cb ^ 1;
        float4 pf[4];
        if (kc < ID / 16 - 1) {
#pragma unroll
            for (int rep = 0; rep < 4; ++rep) {
                const int f = tid + rep * 256;
                const int i = f >> 2, c4 = f & 3;
                pf[rep] = *(const float4*)(ub + (size_t)i * ID + (kc + 1) * 16 + c4 * 4);
            }
        }
#pragma unroll
        for (int k = 0; k < 16; ++k) {
            const float4 a4 = *(const float4*)&Us[cb][k][q * 4];
            const float4 b4a = *(const float4*)&Ts[kc * 16 + k][r * 8];
            const float4 b4b = *(const float4*)&Ts[kc * 16 + k][r * 8 + 4];
            const float av[4] = {a4.x, a4.y, a4.z, a4.w};
            const float bv[8] = {b4a.x, b4a.y, b4a.z, b4a.w,
                                 b4b.x, b4b.y, b4b.z, b4b.w};
#pragma unroll
            for (int ii = 0; ii < 4; ++ii)
#pragma unroll
                for (int jj = 0; jj < 8; ++jj) acc4[ii][jj] += av[ii] * bv[jj];
        }
        if (kc < ID / 16 - 1) {
#pragma unroll
            for (int rep = 0; rep < 4; ++rep) {
                const int f = tid + rep * 256;
                const int i = f >> 2, c4 = f & 3;
                Us[nb][c4 * 4 + 0][i] = pf[rep].x;
                Us[nb][c4 * 4 + 1][i] = pf[rep].y;
                Us[nb][c4 * 4 + 2][i] = pf[rep].z;
                Us[nb][c4 * 4 + 3][i] = pf[rep].w;
            }
        }
    }
#pragma unroll
    for (int ii = 0; ii < 4; ++ii)
#pragma unroll
        for (int jj = 0; jj < 8; ++jj)
            cl[q * 4 + ii][r * 8 + jj] = acc4[ii][jj];
    __syncthreads();

    // softmax over 32 n; thread per i (256 threads = 256 i), no shuffles
    {
        const int i = tid;
        float v[32];
#pragma unroll
        for (int j = 0; j < 32; ++j) v[j] = cl[i][j];
        float mx = v[0];
#pragma unroll
        for (int j = 1; j < 32; ++j) mx = fmaxf(mx, v[j]);
        float sum = 0.f;
#pragma unroll
        for (int j = 0; j < 32; ++j) { v[j] = __expf(v[j] - mx); sum += v[j]; }
        const float inv = 1.0f / sum;
#pragma unroll
        for (int j = 0; j < 32; ++j) cl[i][j] = v[j] * inv;
    }
    __syncthreads();

    // aggregate: thread owns 4 d (float4) x 8 n; u coalesced from L2/L3,
    // coefficients via wave-uniform LDS broadcast.
    const int d4 = tid & 63;
    const int ng = tid >> 6;
    float acc2[8][4];
#pragma unroll
    for (int j = 0; j < 8; ++j)
#pragma unroll
        for (int x = 0; x < 4; ++x) acc2[j][x] = 0.f;
    const float* up = ub + d4 * 4;
#pragma unroll 4
    for (int i = 0; i < RIT; ++i) {
        const float4 uv = *(const float4*)(up + (size_t)i * ID);
        const float4 c0 = *(const float4*)&cl[i][ng * 8];
        const float4 c1 = *(const float4*)&cl[i][ng * 8 + 4];
        const float cv[8] = {c0.x, c0.y, c0.z, c0.w, c1.x, c1.y, c1.z, c1.w};
        const float uvv[4] = {uv.x, uv.y, uv.z, uv.w};
#pragma unroll
        for (int j = 0; j < 8; ++j)
#pragma unroll
            for (int x = 0; x < 4; ++x) acc2[j][x] += cv[j] * uvv[x];
    }
    float* spb = sp + (size_t)(c * B + b) * NC * ID;
#pragma unroll
    for (int j = 0; j < 8; ++j)
        *(float4*)&spb[(size_t)(ng * 8 + j) * ID + d4 * 4] =
            make_float4(acc2[j][0], acc2[j][1], acc2[j][2], acc2[j][3]);
}

// ---------------------------------------------------------------------------
extern "C" void kernel_launch(void* const* d_in, const int* in_sizes, int n_in,
                              void* d_out, int out_size, void* d_ws, size_t ws_size,
                              hipStream_t stream) {
    const float* u = (const float*)d_in[0];   // [B][IN][ID]
    const float* W = (const float*)d_in[1];   // [NC*DC][ID]
    float* out = (float*)d_out;               // [B][NC][DC]

    float* ws  = (float*)d_ws;
    float* t   = ws;                                   // B*NC*ID    = 2 MB
    float* sp  = t  + (size_t)B * NC * ID;             // CH*B*NC*ID = 8 MB
    float* sp0 = sp + (size_t)CH * B * NC * ID;        // CH*B*ID    = 256 KB

    const dim3 blk(256);

    // iteration 0 (uniform c = 1/32)
    k_sumu <<<dim3(CH, B),       blk, 0, stream>>>(u, sp0);
    k_ot   <<<dim3(NC, B / 16),  blk, 0, stream>>>(W, sp0, t, 0);
    // iteration 1
    k_route<<<dim3(CH, B),       blk, 0, stream>>>(u, t, sp);
    k_ot   <<<dim3(NC, B / 16),  blk, 0, stream>>>(W, sp, t, 1);
    // iteration 2
    k_route<<<dim3(CH, B),       blk, 0, stream>>>(u, t, sp);
    k_ot   <<<dim3(NC, B / 16),  blk, 0, stream>>>(W, sp, out, 2);
}